// Round 1
// baseline (13934.581 us; speedup 1.0000x reference)
//
#include <hip/hip_runtime.h>
#include <math.h>

#define DIM 300
#define NNODE 127
#define NB 512
#define BKK 16
#define TILE 64
#define LSTR 68   // padded LDS row stride in floats (68*4B = 272B, 16B-aligned rows)

__device__ __forceinline__ float sigf(float v){ return 1.0f/(1.0f+__expf(-v)); }

// ---------------- Leaf level: nodes 63..126, no children ----------------
__global__ __launch_bounds__(256)
void leaf_kernel(const float* __restrict__ x,
                 const float* __restrict__ Wioux,
                 const float* __restrict__ bioux,
                 const float* __restrict__ biouh,
                 float* __restrict__ H, float* __restrict__ C)
{
    __shared__ float As[BKK*LSTR];
    __shared__ float Bs[3][BKK*LSTR];
    const int t  = threadIdx.x;
    const int d0 = blockIdx.y * TILE;

    const int lk  = t & 15;   // k-col for A loads
    const int lr0 = t >> 4;   // base row for A loads (rows lr0+16i)
    int abase[4];
    #pragma unroll
    for (int i = 0; i < 4; i++){
        int r = blockIdx.x*TILE + lr0 + 16*i;
        int b = r >> 6; int j = 63 + (r & 63);
        abase[i] = (b*NNODE + j)*DIM;
    }
    const int bd = t & 63;    // d-col for B loads
    const int bk = t >> 6;    // loads k rows bk*4 .. bk*4+3
    const int tx = t & 15, ty = t >> 4;

    float ai[16], ao[16], au[16];
    #pragma unroll
    for (int q = 0; q < 16; q++){ ai[q]=0.f; ao[q]=0.f; au[q]=0.f; }

    const bool dok = (d0 + bd) < DIM;
    for (int k0 = 0; k0 < DIM; k0 += BKK){
        #pragma unroll
        for (int i = 0; i < 4; i++){
            int k = k0 + lk;
            As[lk*LSTR + lr0 + 16*i] = (k < DIM) ? x[abase[i] + k] : 0.f;
        }
        #pragma unroll
        for (int g = 0; g < 3; g++){
            #pragma unroll
            for (int ii = 0; ii < 4; ii++){
                int k = k0 + bk*4 + ii;
                Bs[g][(bk*4+ii)*LSTR + bd] =
                    (k < DIM && dok) ? Wioux[k*(3*DIM) + g*DIM + d0 + bd] : 0.f;
            }
        }
        __syncthreads();
        #pragma unroll
        for (int kk = 0; kk < BKK; kk++){
            float ax[4], bi_[4], bo_[4], bu_[4];
            #pragma unroll
            for (int rr = 0; rr < 4; rr++) ax[rr] = As[kk*LSTR + ty*4 + rr];
            #pragma unroll
            for (int cc = 0; cc < 4; cc++){
                bi_[cc] = Bs[0][kk*LSTR + tx*4 + cc];
                bo_[cc] = Bs[1][kk*LSTR + tx*4 + cc];
                bu_[cc] = Bs[2][kk*LSTR + tx*4 + cc];
            }
            #pragma unroll
            for (int rr = 0; rr < 4; rr++)
                #pragma unroll
                for (int cc = 0; cc < 4; cc++){
                    ai[rr*4+cc] += ax[rr]*bi_[cc];
                    ao[rr*4+cc] += ax[rr]*bo_[cc];
                    au[rr*4+cc] += ax[rr]*bu_[cc];
                }
        }
        __syncthreads();
    }
    #pragma unroll
    for (int rr = 0; rr < 4; rr++){
        int r = blockIdx.x*TILE + ty*4 + rr;
        int b = r >> 6; int j = 63 + (r & 63);
        int ob = (b*NNODE + j)*DIM;
        #pragma unroll
        for (int cc = 0; cc < 4; cc++){
            int d = d0 + tx*4 + cc;
            if (d < DIM){
                float iv = sigf (ai[rr*4+cc] + bioux[d]       + biouh[d]);
                float ov = sigf (ao[rr*4+cc] + bioux[DIM+d]   + biouh[DIM+d]);
                float uv = tanhf(au[rr*4+cc] + bioux[2*DIM+d] + biouh[2*DIM+d]);
                float cv = iv*uv;
                C[ob+d] = cv;
                H[ob+d] = ov*tanhf(cv);
            }
        }
    }
}

// ---------------- Internal levels: all gates fused ----------------
__global__ __launch_bounds__(256)
void level_kernel(const float* __restrict__ x,
                  const float* __restrict__ Wioux, const float* __restrict__ bioux,
                  const float* __restrict__ Wiouh, const float* __restrict__ biouh,
                  const float* __restrict__ Wfx,   const float* __restrict__ bfx,
                  const float* __restrict__ Wfh,   const float* __restrict__ bfh,
                  float* __restrict__ H, float* __restrict__ C,
                  int lo, int lshift)
{
    __shared__ float As[3][BKK*LSTR];   // x, h0, h1
    __shared__ float Bs[8][BKK*LSTR];   // Wioux(i,o,u), Wiouh(i,o,u), Wfx, Wfh
    const int t  = threadIdx.x;
    const int d0 = blockIdx.y * TILE;
    const int nmask = (1 << lshift) - 1;

    const int lk  = t & 15;
    const int lr0 = t >> 4;
    int xb[4], h0b[4], h1b[4];
    #pragma unroll
    for (int i = 0; i < 4; i++){
        int r = blockIdx.x*TILE + lr0 + 16*i;
        int b = r >> lshift; int j = lo + (r & nmask);
        xb[i]  = (b*NNODE + j)*DIM;
        h0b[i] = (b*NNODE + 2*j + 1)*DIM;
        h1b[i] = (b*NNODE + 2*j + 2)*DIM;
    }
    const int bd = t & 63;
    const int bk = t >> 6;
    const int tx = t & 15, ty = t >> 4;

    float ai[16], ao[16], au[16], afx[16], af0[16], af1[16];
    #pragma unroll
    for (int q = 0; q < 16; q++){ ai[q]=0.f; ao[q]=0.f; au[q]=0.f; afx[q]=0.f; af0[q]=0.f; af1[q]=0.f; }

    const bool dok = (d0 + bd) < DIM;
    for (int k0 = 0; k0 < DIM; k0 += BKK){
        int k = k0 + lk;
        bool kok = (k < DIM);
        #pragma unroll
        for (int i = 0; i < 4; i++){
            As[0][lk*LSTR + lr0 + 16*i] = kok ? x[xb[i]  + k] : 0.f;
            As[1][lk*LSTR + lr0 + 16*i] = kok ? H[h0b[i] + k] : 0.f;
            As[2][lk*LSTR + lr0 + 16*i] = kok ? H[h1b[i] + k] : 0.f;
        }
        #pragma unroll
        for (int ii = 0; ii < 4; ii++){
            int kb = k0 + bk*4 + ii;
            bool ok = (kb < DIM) && dok;
            int row9 = kb*(3*DIM);
            int row3 = kb*DIM;
            int dd = d0 + bd;
            int ldso = (bk*4+ii)*LSTR + bd;
            Bs[0][ldso] = ok ? Wioux[row9 + dd]         : 0.f;
            Bs[1][ldso] = ok ? Wioux[row9 + DIM + dd]   : 0.f;
            Bs[2][ldso] = ok ? Wioux[row9 + 2*DIM + dd] : 0.f;
            Bs[3][ldso] = ok ? Wiouh[row9 + dd]         : 0.f;
            Bs[4][ldso] = ok ? Wiouh[row9 + DIM + dd]   : 0.f;
            Bs[5][ldso] = ok ? Wiouh[row9 + 2*DIM + dd] : 0.f;
            Bs[6][ldso] = ok ? Wfx[row3 + dd]           : 0.f;
            Bs[7][ldso] = ok ? Wfh[row3 + dd]           : 0.f;
        }
        __syncthreads();
        #pragma unroll
        for (int kk = 0; kk < BKK; kk++){
            float ax[4], a0[4], a1[4], ahs[4];
            #pragma unroll
            for (int rr = 0; rr < 4; rr++){
                ax[rr] = As[0][kk*LSTR + ty*4 + rr];
                a0[rr] = As[1][kk*LSTR + ty*4 + rr];
                a1[rr] = As[2][kk*LSTR + ty*4 + rr];
                ahs[rr] = a0[rr] + a1[rr];
            }
            float bix[4], box[4], bux[4], bih[4], boh[4], buh[4], bfx_[4], bfh_[4];
            #pragma unroll
            for (int cc = 0; cc < 4; cc++){
                int o = kk*LSTR + tx*4 + cc;
                bix[cc]=Bs[0][o]; box[cc]=Bs[1][o]; bux[cc]=Bs[2][o];
                bih[cc]=Bs[3][o]; boh[cc]=Bs[4][o]; buh[cc]=Bs[5][o];
                bfx_[cc]=Bs[6][o]; bfh_[cc]=Bs[7][o];
            }
            #pragma unroll
            for (int rr = 0; rr < 4; rr++)
                #pragma unroll
                for (int cc = 0; cc < 4; cc++){
                    int q = rr*4+cc;
                    ai[q]  += ax[rr]*bix[cc] + ahs[rr]*bih[cc];
                    ao[q]  += ax[rr]*box[cc] + ahs[rr]*boh[cc];
                    au[q]  += ax[rr]*bux[cc] + ahs[rr]*buh[cc];
                    afx[q] += ax[rr]*bfx_[cc];
                    af0[q] += a0[rr]*bfh_[cc];
                    af1[q] += a1[rr]*bfh_[cc];
                }
        }
        __syncthreads();
    }
    #pragma unroll
    for (int rr = 0; rr < 4; rr++){
        int r = blockIdx.x*TILE + ty*4 + rr;
        int b = r >> lshift; int j = lo + (r & nmask);
        int ob  = (b*NNODE + j)*DIM;
        int cb0 = (b*NNODE + 2*j + 1)*DIM;
        int cb1 = (b*NNODE + 2*j + 2)*DIM;
        #pragma unroll
        for (int cc = 0; cc < 4; cc++){
            int d = d0 + tx*4 + cc;
            if (d < DIM){
                int q = rr*4+cc;
                float iv = sigf (ai[q] + bioux[d]       + biouh[d]);
                float ov = sigf (ao[q] + bioux[DIM+d]   + biouh[DIM+d]);
                float uv = tanhf(au[q] + bioux[2*DIM+d] + biouh[2*DIM+d]);
                float fb = bfx[d] + bfh[d];
                float f0 = sigf(afx[q] + af0[q] + fb);
                float f1 = sigf(afx[q] + af1[q] + fb);
                float cv = iv*uv + f0*C[cb0+d] + f1*C[cb1+d];
                C[ob+d] = cv;
                H[ob+d] = ov*tanhf(cv);
            }
        }
    }
}

extern "C" void kernel_launch(void* const* d_in, const int* in_sizes, int n_in,
                              void* d_out, int out_size, void* d_ws, size_t ws_size,
                              hipStream_t stream) {
    const float* x     = (const float*)d_in[0];
    const float* Wioux = (const float*)d_in[1];
    const float* bioux = (const float*)d_in[2];
    const float* Wiouh = (const float*)d_in[3];
    const float* biouh = (const float*)d_in[4];
    const float* Wfx   = (const float*)d_in[5];
    const float* bfx   = (const float*)d_in[6];
    const float* Wfh   = (const float*)d_in[7];
    const float* bfh   = (const float*)d_in[8];
    float* H = (float*)d_out;
    float* C = (float*)d_ws;   // 512*127*300*4 = 78 MB of scratch for cell state

    dim3 blk(256);
    // leaves: 64 nodes -> 32768 rows, 512 row-tiles x 5 col-tiles
    leaf_kernel<<<dim3(512, 5), blk, 0, stream>>>(x, Wioux, bioux, biouh, H, C);
    // internal levels, deepest first: l = 5..0, n = 2^l nodes, lo = 2^l - 1
    for (int l = 5; l >= 0; l--){
        int n = 1 << l;
        level_kernel<<<dim3(8*n, 5), blk, 0, stream>>>(
            x, Wioux, bioux, Wiouh, biouh, Wfx, bfx, Wfh, bfh, H, C,
            n - 1, l);
    }
}

// Round 2
// 533.812 us; speedup vs baseline: 26.1039x; 26.1039x over previous
//
#include <hip/hip_runtime.h>
#include <math.h>

#define DIM 300
#define NNODE 127
#define KP 320              // K padded to 10 x 32
#define BK 32
#define ASTR 40             // LDS row stride in shorts (80 B: 16B-aligned, 2-way bank aliasing = free)
#define MATSZ (KP*KP)       // elements per transposed weight matrix

typedef __attribute__((ext_vector_type(8)))  short bf16x8;
typedef __attribute__((ext_vector_type(16))) float f32x16;

__device__ __forceinline__ unsigned short f2bf(float f){
    unsigned u = __float_as_uint(f);
    u += 0x7fffu + ((u >> 16) & 1u);       // round-to-nearest-even
    return (unsigned short)(u >> 16);
}
__device__ __forceinline__ float sigf(float v){ return 1.0f/(1.0f+__expf(-v)); }
__device__ __forceinline__ float tanh_(float v){
    float t = __expf(-2.0f*fabsf(v));
    float r = (1.0f - t)/(1.0f + t);
    return v < 0.0f ? -r : r;
}

// ---- one-time: transpose + bf16-convert weights into WT[8][320][320] ([n][k]) ----
// mats 0..2: Wioux gates i,o,u ; 3..5: Wiouh ; 6: Wfx ; 7: Wfh. Pad rows/cols with 0.
__global__ void prep_weights(const float* __restrict__ Wioux,
                             const float* __restrict__ Wiouh,
                             const float* __restrict__ Wfx,
                             const float* __restrict__ Wfh,
                             unsigned short* __restrict__ WT)
{
    int k = threadIdx.x;     // 0..319
    int n = blockIdx.x;      // 0..319
    int m = blockIdx.y;      // 0..7
    float v = 0.f;
    if (k < DIM && n < DIM){
        if (m < 3)       v = Wioux[k*(3*DIM) + m*DIM + n];
        else if (m < 6)  v = Wiouh[k*(3*DIM) + (m-3)*DIM + n];
        else if (m == 6) v = Wfx[k*DIM + n];
        else             v = Wfh[k*DIM + n];
    }
    WT[m*MATSZ + n*KP + k] = f2bf(v);
}

// ---- leaf level (nodes 63..126): iou GEMM only, c = i*u ----
__global__ __launch_bounds__(256,2)
void leaf_mfma(const float* __restrict__ x,
               const float* __restrict__ bioux, const float* __restrict__ biouh,
               const unsigned short* __restrict__ WT,
               float* __restrict__ H, float* __restrict__ C)
{
    __shared__ __attribute__((aligned(16))) short lds[(1+3)*64*ASTR];
    short* As = lds;                 // x tile: 64 rows x 32 k
    short* Bs = lds + 64*ASTR;       // 3 mats x 64 n x 32 k

    const int t = threadIdx.x;
    const int lane = t & 63, wave = t >> 6;
    const int wm = wave >> 1, wn = wave & 1;
    const int lrow = lane & 31, half = lane >> 5;
    const int rowBase = blockIdx.x * 64;
    const int d0 = blockIdx.y * 64;

    // A staging role: 4 threads per row, 8 floats each
    const int sr = t >> 2, sseg = t & 3;
    const float* xrow;
    {
        int grow = rowBase + sr;
        int b = grow >> 6, j = 63 + (grow & 63);
        xrow = x + (b*NNODE + j)*DIM;
    }
    // B staging role: mats 0..2 on threads 0..95
    const int bm = t >> 5, bn = t & 31;

    f32x16 accI, accO, accU;
    #pragma unroll
    for (int i = 0; i < 16; i++){ accI[i]=0.f; accO[i]=0.f; accU[i]=0.f; }

    for (int k0 = 0; k0 < KP; k0 += BK){
        // A stage
        {
            int kk0 = k0 + sseg*8;
            bf16x8 px;
            if (kk0 + 8 <= DIM){
                float4 a0 = *(const float4*)(xrow + kk0);
                float4 a1 = *(const float4*)(xrow + kk0 + 4);
                px[0]=f2bf(a0.x); px[1]=f2bf(a0.y); px[2]=f2bf(a0.z); px[3]=f2bf(a0.w);
                px[4]=f2bf(a1.x); px[5]=f2bf(a1.y); px[6]=f2bf(a1.z); px[7]=f2bf(a1.w);
            } else {
                #pragma unroll
                for (int e = 0; e < 8; e++){
                    int k = kk0 + e;
                    px[e] = f2bf(k < DIM ? xrow[k] : 0.f);
                }
            }
            *(bf16x8*)(As + sr*ASTR + sseg*8) = px;
        }
        // B stage (3 mats)
        if (bm < 3){
            const unsigned short* wb = WT + bm*MATSZ + k0;
            #pragma unroll
            for (int h2 = 0; h2 < 2; h2++){
                int nn = bn + 32*h2;
                const unsigned short* src = wb + (d0 + nn)*KP;
                short* dst = Bs + bm*64*ASTR + nn*ASTR;
                *(bf16x8*)(dst)      = *(const bf16x8*)(src);
                *(bf16x8*)(dst + 8)  = *(const bf16x8*)(src + 8);
                *(bf16x8*)(dst + 16) = *(const bf16x8*)(src + 16);
                *(bf16x8*)(dst + 24) = *(const bf16x8*)(src + 24);
            }
        }
        __syncthreads();
        #pragma unroll
        for (int kk = 0; kk < 2; kk++){
            int ao = (wm*32 + lrow)*ASTR + kk*16 + half*8;
            bf16x8 ax = *(const bf16x8*)(As + ao);
            int bo = (wn*32 + lrow)*ASTR + kk*16 + half*8;
            bf16x8 b0 = *(const bf16x8*)(Bs + 0*64*ASTR + bo);
            bf16x8 b1 = *(const bf16x8*)(Bs + 1*64*ASTR + bo);
            bf16x8 b2 = *(const bf16x8*)(Bs + 2*64*ASTR + bo);
            accI = __builtin_amdgcn_mfma_f32_32x32x16_bf16(ax, b0, accI, 0, 0, 0);
            accO = __builtin_amdgcn_mfma_f32_32x32x16_bf16(ax, b1, accO, 0, 0, 0);
            accU = __builtin_amdgcn_mfma_f32_32x32x16_bf16(ax, b2, accU, 0, 0, 0);
        }
        __syncthreads();
    }
    // epilogue
    int d = d0 + wn*32 + lrow;
    if (d < DIM){
        float bi  = bioux[d]       + biouh[d];
        float bo_ = bioux[DIM+d]   + biouh[DIM+d];
        float bu  = bioux[2*DIM+d] + biouh[2*DIM+d];
        #pragma unroll
        for (int q = 0; q < 16; q++){
            int grow = rowBase + wm*32 + (q&3) + 8*(q>>2) + 4*half;
            int b = grow >> 6, j = 63 + (grow & 63);
            int obase = (b*NNODE + j)*DIM + d;
            float iv = sigf (accI[q] + bi);
            float ov = sigf (accO[q] + bo_);
            float uv = tanh_(accU[q] + bu);
            float cv = iv*uv;
            C[obase] = cv;
            H[obase] = ov*tanh_(cv);
        }
    }
}

// ---- internal levels: 6 fused accumulator groups ----
__global__ __launch_bounds__(256,2)
void level_mfma(const float* __restrict__ x,
                const float* __restrict__ bioux, const float* __restrict__ biouh,
                const float* __restrict__ bfx,   const float* __restrict__ bfh,
                const unsigned short* __restrict__ WT,
                float* __restrict__ H, float* __restrict__ C,
                int lo, int lshift)
{
    __shared__ __attribute__((aligned(16))) short lds[(4+8)*64*ASTR];  // 60 KB
    short* As = lds;                  // ops: 0=x 1=hsum 2=h0 3=h1
    short* Bs = lds + 4*64*ASTR;      // 8 mats x 64 n x 32 k

    const int t = threadIdx.x;
    const int lane = t & 63, wave = t >> 6;
    const int wm = wave >> 1, wn = wave & 1;
    const int lrow = lane & 31, half = lane >> 5;
    const int rowBase = blockIdx.x * 64;
    const int d0 = blockIdx.y * 64;
    const int nmask = (1 << lshift) - 1;

    const int sr = t >> 2, sseg = t & 3;
    const float *xrow, *h0row, *h1row;
    {
        int grow = rowBase + sr;
        int b = grow >> lshift, j = lo + (grow & nmask);
        xrow  = x + (b*NNODE + j)*DIM;
        h0row = H + (b*NNODE + 2*j+1)*DIM;
        h1row = H + (b*NNODE + 2*j+2)*DIM;
    }
    const int bm = t >> 5, bn = t & 31;

    f32x16 accI, accO, accU, accFx, accF0, accF1;
    #pragma unroll
    for (int i = 0; i < 16; i++){
        accI[i]=0.f; accO[i]=0.f; accU[i]=0.f;
        accFx[i]=0.f; accF0[i]=0.f; accF1[i]=0.f;
    }

    for (int k0 = 0; k0 < KP; k0 += BK){
        // ---- A stage: x, then h0/h1/hsum ----
        {
            int kk0 = k0 + sseg*8;
            int aoff = sr*ASTR + sseg*8;
            bf16x8 px;
            if (kk0 + 8 <= DIM){
                float4 a0 = *(const float4*)(xrow + kk0);
                float4 a1 = *(const float4*)(xrow + kk0 + 4);
                px[0]=f2bf(a0.x); px[1]=f2bf(a0.y); px[2]=f2bf(a0.z); px[3]=f2bf(a0.w);
                px[4]=f2bf(a1.x); px[5]=f2bf(a1.y); px[6]=f2bf(a1.z); px[7]=f2bf(a1.w);
            } else {
                #pragma unroll
                for (int e = 0; e < 8; e++){
                    int k = kk0 + e;
                    px[e] = f2bf(k < DIM ? xrow[k] : 0.f);
                }
            }
            *(bf16x8*)(As + aoff) = px;

            float h0v[8], h1v[8];
            if (kk0 + 8 <= DIM){
                float4 b0 = *(const float4*)(h0row + kk0);
                float4 b1 = *(const float4*)(h0row + kk0 + 4);
                float4 c0 = *(const float4*)(h1row + kk0);
                float4 c1 = *(const float4*)(h1row + kk0 + 4);
                h0v[0]=b0.x; h0v[1]=b0.y; h0v[2]=b0.z; h0v[3]=b0.w;
                h0v[4]=b1.x; h0v[5]=b1.y; h0v[6]=b1.z; h0v[7]=b1.w;
                h1v[0]=c0.x; h1v[1]=c0.y; h1v[2]=c0.z; h1v[3]=c0.w;
                h1v[4]=c1.x; h1v[5]=c1.y; h1v[6]=c1.z; h1v[7]=c1.w;
            } else {
                #pragma unroll
                for (int e = 0; e < 8; e++){
                    int k = kk0 + e;
                    bool ok = k < DIM;
                    h0v[e] = ok ? h0row[k] : 0.f;
                    h1v[e] = ok ? h1row[k] : 0.f;
                }
            }
            bf16x8 ph, p0, p1;
            #pragma unroll
            for (int e = 0; e < 8; e++){
                p0[e] = f2bf(h0v[e]);
                p1[e] = f2bf(h1v[e]);
                ph[e] = f2bf(h0v[e] + h1v[e]);
            }
            *(bf16x8*)(As + 1*64*ASTR + aoff) = ph;
            *(bf16x8*)(As + 2*64*ASTR + aoff) = p0;
            *(bf16x8*)(As + 3*64*ASTR + aoff) = p1;
        }
        // ---- B stage: 8 mats x 64 n-rows x 32 k ----
        {
            const unsigned short* wb = WT + bm*MATSZ + k0;
            #pragma unroll
            for (int h2 = 0; h2 < 2; h2++){
                int nn = bn + 32*h2;
                const unsigned short* src = wb + (d0 + nn)*KP;
                short* dst = Bs + bm*64*ASTR + nn*ASTR;
                *(bf16x8*)(dst)      = *(const bf16x8*)(src);
                *(bf16x8*)(dst + 8)  = *(const bf16x8*)(src + 8);
                *(bf16x8*)(dst + 16) = *(const bf16x8*)(src + 16);
                *(bf16x8*)(dst + 24) = *(const bf16x8*)(src + 24);
            }
        }
        __syncthreads();
        // ---- MFMA: 9 per k-step per wave ----
        #pragma unroll
        for (int kk = 0; kk < 2; kk++){
            int ao = (wm*32 + lrow)*ASTR + kk*16 + half*8;
            bf16x8 ax = *(const bf16x8*)(As + 0*64*ASTR + ao);
            bf16x8 ah = *(const bf16x8*)(As + 1*64*ASTR + ao);
            bf16x8 a0 = *(const bf16x8*)(As + 2*64*ASTR + ao);
            bf16x8 a1 = *(const bf16x8*)(As + 3*64*ASTR + ao);
            int bo = (wn*32 + lrow)*ASTR + kk*16 + half*8;
            bf16x8 b0 = *(const bf16x8*)(Bs + 0*64*ASTR + bo);
            bf16x8 b1 = *(const bf16x8*)(Bs + 1*64*ASTR + bo);
            bf16x8 b2 = *(const bf16x8*)(Bs + 2*64*ASTR + bo);
            bf16x8 b3 = *(const bf16x8*)(Bs + 3*64*ASTR + bo);
            bf16x8 b4 = *(const bf16x8*)(Bs + 4*64*ASTR + bo);
            bf16x8 b5 = *(const bf16x8*)(Bs + 5*64*ASTR + bo);
            bf16x8 b6 = *(const bf16x8*)(Bs + 6*64*ASTR + bo);
            bf16x8 b7 = *(const bf16x8*)(Bs + 7*64*ASTR + bo);
            accI  = __builtin_amdgcn_mfma_f32_32x32x16_bf16(ax, b0, accI , 0, 0, 0);
            accI  = __builtin_amdgcn_mfma_f32_32x32x16_bf16(ah, b3, accI , 0, 0, 0);
            accO  = __builtin_amdgcn_mfma_f32_32x32x16_bf16(ax, b1, accO , 0, 0, 0);
            accO  = __builtin_amdgcn_mfma_f32_32x32x16_bf16(ah, b4, accO , 0, 0, 0);
            accU  = __builtin_amdgcn_mfma_f32_32x32x16_bf16(ax, b2, accU , 0, 0, 0);
            accU  = __builtin_amdgcn_mfma_f32_32x32x16_bf16(ah, b5, accU , 0, 0, 0);
            accFx = __builtin_amdgcn_mfma_f32_32x32x16_bf16(ax, b6, accFx, 0, 0, 0);
            accF0 = __builtin_amdgcn_mfma_f32_32x32x16_bf16(a0, b7, accF0, 0, 0, 0);
            accF1 = __builtin_amdgcn_mfma_f32_32x32x16_bf16(a1, b7, accF1, 0, 0, 0);
        }
        __syncthreads();
    }
    // ---- epilogue ----
    int d = d0 + wn*32 + lrow;
    if (d < DIM){
        float bi  = bioux[d]       + biouh[d];
        float bo_ = bioux[DIM+d]   + biouh[DIM+d];
        float bu  = bioux[2*DIM+d] + biouh[2*DIM+d];
        float bf_ = bfx[d] + bfh[d];
        #pragma unroll
        for (int q = 0; q < 16; q++){
            int grow = rowBase + wm*32 + (q&3) + 8*(q>>2) + 4*half;
            int b = grow >> lshift, j = lo + (grow & nmask);
            int obase = (b*NNODE + j)*DIM + d;
            int c0i = (b*NNODE + 2*j+1)*DIM + d;
            int c1i = (b*NNODE + 2*j+2)*DIM + d;
            float iv = sigf (accI[q] + bi);
            float ov = sigf (accO[q] + bo_);
            float uv = tanh_(accU[q] + bu);
            float f0 = sigf (accFx[q] + accF0[q] + bf_);
            float f1 = sigf (accFx[q] + accF1[q] + bf_);
            float cv = iv*uv + f0*C[c0i] + f1*C[c1i];
            C[obase] = cv;
            H[obase] = ov*tanh_(cv);
        }
    }
}

extern "C" void kernel_launch(void* const* d_in, const int* in_sizes, int n_in,
                              void* d_out, int out_size, void* d_ws, size_t ws_size,
                              hipStream_t stream) {
    const float* x     = (const float*)d_in[0];
    const float* Wioux = (const float*)d_in[1];
    const float* bioux = (const float*)d_in[2];
    const float* Wiouh = (const float*)d_in[3];
    const float* biouh = (const float*)d_in[4];
    const float* Wfx   = (const float*)d_in[5];
    const float* bfx   = (const float*)d_in[6];
    const float* Wfh   = (const float*)d_in[7];
    const float* bfh   = (const float*)d_in[8];
    float* H = (float*)d_out;
    float* C = (float*)d_ws;                                   // 78,028,800 B
    unsigned short* WT = (unsigned short*)((char*)d_ws + 78028800);  // 1,638,400 B

    prep_weights<<<dim3(KP, 8), KP, 0, stream>>>(Wioux, Wiouh, Wfx, Wfh, WT);
    // leaves: 64 nodes -> 32768 rows
    leaf_mfma<<<dim3(512, 5), 256, 0, stream>>>(x, bioux, biouh, WT, H, C);
    // internal levels deepest-first
    for (int l = 5; l >= 0; l--){
        level_mfma<<<dim3(8 << l, 5), 256, 0, stream>>>(
            x, bioux, biouh, bfx, bfh, WT, H, C, (1 << l) - 1, l);
    }
}